// Round 4
// 1867.549 us; speedup vs baseline: 1.6924x; 1.6924x over previous
//
#include <hip/hip_runtime.h>
#include <hip/hip_bf16.h>

// LSTM: B=256, T=512, D=512, H=512, fp32 in/out, fp16 compute (fp32 accum).
//   k_prep    : cast x -> f16; transpose+permute Wx,Wh -> [n'][k] f16 (n' = j*4+gate); permute b.
//   k_gemm_xg : xg[b*T+t][n'] = x @ Wx + b   (m97-style 128x128 MFMA tile, f16 out)
//   k_scan    : cooperative, 16 groups x 16 blocks (XCD-local groups). Block s owns 32 hidden
//               units (128 gate cols) for its group's 16 batch rows. Wh slice pinned in VGPRs.
//               Swapped MFMA (A=Wh, B=h): lane gets full i,f,g,o quad per (m,j) -> no LDS.
//               r9 = PROVEN r5 flag protocol (sentinel arc r6-r8 failed with identical,
//               cache-op-invariant absmax -> deterministic flaw, reverted) + two safe cuts:
//                 (A) single-wave flag poll: only wave 0 polls the 16 flags, then
//                     __syncthreads releases waves 1-3. 4x less poll traffic on the
//                     group's flag lines at the coherence point; protocol unchanged.
//                 (B) h loads as 16x16B sc0 sc1 dwordx4 (was 32x8B relaxed-agent atomics):
//                     same addresses, same coherence point, issued strictly after flag
//                     observation (control dep + membar + barrier) -> r5 visibility
//                     guarantee intact; explicit vmcnt(0)+sched_barrier before MFMA.
//               Producer side unchanged: contiguous 16B/lane sc0 sc1 store per wave ->
//               s_waitcnt vmcnt(0) (ack at coherence point) -> per-wave flag atomicAdd.

typedef _Float16 half8 __attribute__((ext_vector_type(8)));
typedef _Float16 half4 __attribute__((ext_vector_type(4)));
typedef int int4v __attribute__((ext_vector_type(4)));
typedef float float4v __attribute__((ext_vector_type(4)));

__device__ __forceinline__ void gl_lds16(const void* g, void* l) {
  __builtin_amdgcn_global_load_lds(
      (const __attribute__((address_space(1))) unsigned int*)g,
      (__attribute__((address_space(3))) unsigned int*)l, 16, 0, 0);
}

__device__ __forceinline__ float sigm(float v) { return 1.f / (1.f + __expf(-v)); }
__device__ __forceinline__ float tanh_(float v) { return 1.f - 2.f / (__expf(2.f * v) + 1.f); }

// ---------------------------------------------------------------- k_prep
__global__ __launch_bounds__(256) void k_prep(
    const float* __restrict__ x, const float* __restrict__ Wx,
    const float* __restrict__ Wh, const float* __restrict__ b,
    _Float16* __restrict__ xf, _Float16* __restrict__ wxt,
    _Float16* __restrict__ wht, float* __restrict__ bp)
{
  const long NX8 = 67108864L / 8;   // x elems / 8
  const long NW  = 2048L * 512;     // one transposed weight matrix
  const long TOT = NX8 + 2 * NW + 2048;
  long stride = (long)gridDim.x * blockDim.x;
  for (long id = (long)blockIdx.x * blockDim.x + threadIdx.x; id < TOT; id += stride) {
    if (id < NX8) {
      const float4v* p = (const float4v*)x + id * 2;
      float4v a = p[0], c = p[1];
      half8 o;
      o[0]=(_Float16)a[0]; o[1]=(_Float16)a[1]; o[2]=(_Float16)a[2]; o[3]=(_Float16)a[3];
      o[4]=(_Float16)c[0]; o[5]=(_Float16)c[1]; o[6]=(_Float16)c[2]; o[7]=(_Float16)c[3];
      ((half8*)xf)[id] = o;
    } else if (id < NX8 + NW) {
      long e = id - NX8;
      int np = (int)(e >> 9), k = (int)(e & 511);
      int j = np >> 2, gt = np & 3;               // n' = j*4 + gate
      wxt[e] = (_Float16)Wx[(long)k * 2048 + gt * 512 + j];
    } else if (id < NX8 + 2 * NW) {
      long e = id - NX8 - NW;
      int np = (int)(e >> 9), k = (int)(e & 511);
      int j = np >> 2, gt = np & 3;
      wht[e] = (_Float16)Wh[(long)k * 2048 + gt * 512 + j];
    } else {
      int np = (int)(id - NX8 - 2 * NW);
      int j = np >> 2, gt = np & 3;
      bp[np] = b[gt * 512 + j];
    }
  }
}

// ---------------------------------------------------------------- k_gemm_xg
// C[M=131072][N=2048] = xf[M][512] @ wxt[N][512]^T + bp, f16 out.
__global__ __launch_bounds__(256, 2) void k_gemm_xg(
    const _Float16* __restrict__ xf, const _Float16* __restrict__ wxt,
    const float* __restrict__ bp, _Float16* __restrict__ xg)
{
  __shared__ _Float16 As[128 * 32];
  __shared__ _Float16 Bs[128 * 32];
  const int tid = threadIdx.x;
  const int w = tid >> 6, l = tid & 63;
  const int mt = blockIdx.x >> 4, nt = blockIdx.x & 15;
  const int qr = (w >> 1) * 64, qc = (w & 1) * 64;
  float4v acc[4][4];
  #pragma unroll
  for (int i = 0; i < 4; ++i)
    #pragma unroll
    for (int j = 0; j < 4; ++j) acc[i][j] = (float4v){0.f, 0.f, 0.f, 0.f};
  const int lr = l >> 2, lc = (l & 3) * 8;
  for (int kt = 0; kt < 16; ++kt) {
    __syncthreads();
    #pragma unroll
    for (int i = 0; i < 2; ++i) {
      int chunk = i * 4 + w;  // 16 rows x 64B per chunk; lane writes base + lane*16B
      gl_lds16(xf + ((long)(mt * 128 + chunk * 16 + lr)) * 512 + kt * 32 + lc, As + chunk * 512);
      gl_lds16(wxt + ((long)(nt * 128 + chunk * 16 + lr)) * 512 + kt * 32 + lc, Bs + chunk * 512);
    }
    __syncthreads();
    half8 af[4], bf[4];
    #pragma unroll
    for (int mi = 0; mi < 4; ++mi)
      af[mi] = *(const half8*)(As + (qr + mi * 16 + (l & 15)) * 32 + (l >> 4) * 8);
    #pragma unroll
    for (int ni = 0; ni < 4; ++ni)
      bf[ni] = *(const half8*)(Bs + (qc + ni * 16 + (l & 15)) * 32 + (l >> 4) * 8);
    #pragma unroll
    for (int mi = 0; mi < 4; ++mi)
      #pragma unroll
      for (int ni = 0; ni < 4; ++ni)
        acc[mi][ni] = __builtin_amdgcn_mfma_f32_16x16x32_f16(af[mi], bf[ni], acc[mi][ni], 0, 0, 0);
  }
  #pragma unroll
  for (int ni = 0; ni < 4; ++ni) {
    int col = nt * 128 + qc + ni * 16 + (l & 15);
    float bias = bp[col];
    #pragma unroll
    for (int mi = 0; mi < 4; ++mi) {
      long R0 = (long)mt * 128 + qr + mi * 16 + (l >> 4) * 4;
      #pragma unroll
      for (int r = 0; r < 4; ++r)
        xg[(R0 + r) * 2048 + col] = (_Float16)(acc[mi][ni][r] + bias);
    }
  }
}

// ---------------------------------------------------------------- k_scan
// hsl: f16 [2 parity][256 slices][512], slice = 1KB, layout [w4][m16][8j'].
// flags: u32 arrival counters, 64B apart, flags[g*256 + s*16]: +1 per wave per step.
__global__ __launch_bounds__(256, 1) void k_scan(
    const _Float16* __restrict__ xg, const _Float16* __restrict__ wht,
    const float* __restrict__ wfc, const float* __restrict__ bfc,
    _Float16* __restrict__ hsl, unsigned int* __restrict__ flags,
    float* __restrict__ out)
{
  const int tid = threadIdx.x;
  const int w = tid >> 6, l = tid & 63;
  const int q = l >> 4;            // k-subslice selector / j-quad
  const int m = l & 15;            // batch row within group
  const int bb = blockIdx.x;
  const int slot = bb >> 3;
  const int g = (bb & 7) * 2 + (slot >> 4);   // XCD-local group placement (perf only)
  const int s = slot & 15;

  // Wh A-fragments, pinned in VGPRs. Tile nt=2w+e rows n' = s*128 + nt*16 + m, k = kk*32 + q*8..
  int4v bw0[16], bw1[16];
  {
    const _Float16* b0 = wht + ((long)(s * 128 + (2 * w + 0) * 16 + m)) * 512 + q * 8;
    const _Float16* b1 = wht + ((long)(s * 128 + (2 * w + 1) * 16 + m)) * 512 + q * 8;
    #pragma unroll
    for (int kk = 0; kk < 16; ++kk) {
      bw0[kk] = *(const int4v*)(b0 + kk * 32);
      bw1[kk] = *(const int4v*)(b1 + kk * 32);
    }
    #pragma unroll
    for (int kk = 0; kk < 16; ++kk)
      asm volatile("" : "+v"(bw0[kk]), "+v"(bw1[kk]));  // force residency; no remat
  }

  float c0 = 0.f, c1 = 0.f;
  const int j0 = s * 32 + 8 * w + q;              // this lane's two hidden units
  const int j1 = s * 32 + 8 * w + 4 + q;
  const float wf0 = wfc[j0], wf1 = wfc[j1];
  unsigned int* fl = flags + g * 256;             // 16 counters * 16 u32 stride (64B lines)
  const _Float16* xgr = xg + ((long)(g * 16 + m)) * 512 * 2048 + s * 128 + q * 4;
  const _Float16* hrg = hsl + (long)g * 8192 + q * 128 + m * 8;
  _Float16* hw = hsl + (long)(g * 16 + s) * 512 + w * 128 + m * 8;

  for (int t = 0; t < 512; ++t) {
    const int pr = t & 1;
    // prefetch this step's xg quads (plain cached loads; latency hides under poll)
    const half4 xv0 = *(const half4*)(xgr + (long)t * 2048 + (2 * w + 0) * 16);
    const half4 xv1 = *(const half4*)(xgr + (long)t * 2048 + (2 * w + 1) * 16);
    if (t) {
      // (A) single-wave poll: wave 0's lanes 0..15 poll the 16 flags; barrier
      // releases waves 1-3. 4x less device-visible poll traffic than r5.
      if (w == 0 && l < 16) {
        unsigned int* p = fl + l * 16;
        while (__hip_atomic_load(p, __ATOMIC_RELAXED, __HIP_MEMORY_SCOPE_AGENT)
               < 4u * (unsigned)t) {}
      }
      asm volatile("" ::: "memory");   // compile-time order only; no cache ops
      __syncthreads();
    }
    // (B) load group's h_t as 16x16B sc0 sc1 loads (coherence-point reads, issued
    // strictly after flag observation -> producer's acked data is visible).
    const _Float16* hr = hrg + pr * 131072;
    int4v av[16];
    #pragma unroll
    for (int kk = 0; kk < 16; ++kk)
      asm volatile("global_load_dwordx4 %0, %1, off sc0 sc1"
                   : "=&v"(av[kk]) : "v"(hr + kk * 512) : "memory");
    asm volatile("s_waitcnt vmcnt(0)" ::: "memory");
    __builtin_amdgcn_sched_barrier(0);   // rule #18: no MFMA hoist past the waitcnt

    float4v a0 = (float4v){0.f,0.f,0.f,0.f}, a1 = a0, b0v = a0, b1v = a0;
    #pragma unroll
    for (int kk = 0; kk < 8; ++kk) {
      a0 = __builtin_amdgcn_mfma_f32_16x16x32_f16(__builtin_bit_cast(half8, bw0[kk]),
                                                  __builtin_bit_cast(half8, av[kk]), a0, 0, 0, 0);
      a1 = __builtin_amdgcn_mfma_f32_16x16x32_f16(__builtin_bit_cast(half8, bw1[kk]),
                                                  __builtin_bit_cast(half8, av[kk]), a1, 0, 0, 0);
    }
    #pragma unroll
    for (int kk = 8; kk < 16; ++kk) {
      b0v = __builtin_amdgcn_mfma_f32_16x16x32_f16(__builtin_bit_cast(half8, bw0[kk]),
                                                   __builtin_bit_cast(half8, av[kk]), b0v, 0, 0, 0);
      b1v = __builtin_amdgcn_mfma_f32_16x16x32_f16(__builtin_bit_cast(half8, bw1[kk]),
                                                   __builtin_bit_cast(half8, av[kk]), b1v, 0, 0, 0);
    }
    a0 += b0v; a1 += b1v;
    // lane holds full gate quad (i,f,g,o) for (m, j0) in a0 and (m, j1) in a1
    float i0 = sigm(a0[0] + (float)xv0[0]);
    float f0 = sigm(a0[1] + (float)xv0[1]);
    float g0 = tanh_(a0[2] + (float)xv0[2]);
    float o0 = sigm(a0[3] + (float)xv0[3]);
    c0 = f0 * c0 + i0 * g0;
    float h0v = o0 * tanh_(c0);
    float i1 = sigm(a1[0] + (float)xv1[0]);
    float f1 = sigm(a1[1] + (float)xv1[1]);
    float g1 = tanh_(a1[2] + (float)xv1[2]);
    float o1 = sigm(a1[3] + (float)xv1[3]);
    c1 = f1 * c1 + i1 * g1;
    float h1v = o1 * tanh_(c1);
    // gather 8 f16 (j' = 8w..8w+7 for row m) into lane q==0, publish one 16B coherent store
    unsigned int hb0 = (unsigned int)__builtin_bit_cast(unsigned short, (_Float16)h0v);
    unsigned int hb1 = (unsigned int)__builtin_bit_cast(unsigned short, (_Float16)h1v);
    unsigned int pb0 = __shfl_xor(hb0, 16);
    unsigned int pb1 = __shfl_xor(hb1, 16);
    unsigned int pair0 = hb0 | (pb0 << 16);   // (8w+q, 8w+q+1) at even q
    unsigned int pair1 = hb1 | (pb1 << 16);   // (8w+4+q, 8w+5+q) at even q
    unsigned int x0 = __shfl_xor(pair0, 32);  // q=0 <-> q=2
    unsigned int x1 = __shfl_xor(pair1, 32);
    if (q == 0) {
      int4v pk = {(int)pair0, (int)x0, (int)pair1, (int)x1};  // j' 0..7 of this wave's block
      _Float16* dst = hw + (pr ^ 1) * 131072;
      asm volatile("global_store_dwordx4 %0, %1, off sc0 sc1"
                   :: "v"(dst), "v"(pk) : "memory");
    }
    if (t == 511) {
      float part = h0v * wf0 + h1v * wf1;
      part += __shfl_xor(part, 16);
      part += __shfl_xor(part, 32);
      if (l < 16) {
        float v = part;
        if (s == 0 && w == 0) v += bfc[0];
        atomicAdd(out + g * 16 + l, v);
      }
    } else {
      // release: coherent stores ACK at coherence point, then signal arrival (per wave)
      asm volatile("s_waitcnt vmcnt(0)" ::: "memory");
      if (l == 0)
        (void)__hip_atomic_fetch_add(fl + s * 16, 1u, __ATOMIC_RELAXED,
                                     __HIP_MEMORY_SCOPE_AGENT);
    }
  }
}

// ---------------------------------------------------------------- launch
extern "C" void kernel_launch(void* const* d_in, const int* in_sizes, int n_in,
                              void* d_out, int out_size, void* d_ws, size_t ws_size,
                              hipStream_t stream)
{
  const float* x   = (const float*)d_in[0];
  const float* Wx  = (const float*)d_in[1];
  const float* Wh  = (const float*)d_in[2];
  const float* b   = (const float*)d_in[3];
  const float* Wfc = (const float*)d_in[4];
  const float* bfc = (const float*)d_in[5];
  char* ws = (char*)d_ws;

  const size_t OFF_XG  = 0;                          // f16 [131072][2048] = 512MB
  const size_t OFF_XB  = 536870912UL;                // f16 x          = 128MB
  const size_t OFF_WXT = OFF_XB + 134217728UL;       // f16 [2048][512] = 2MB
  const size_t OFF_WHT = OFF_WXT + 2097152UL;        // f16 [2048][512] = 2MB
  const size_t OFF_BP  = OFF_WHT + 2097152UL;        // f32 [2048]
  const size_t OFF_H   = OFF_BP + 8192UL;            // f16 [2][256][512] = 512KB
  const size_t OFF_FL  = OFF_H + 524288UL;           // u32 flags, 64B apart = 16KB
  const size_t NEED    = OFF_FL + 16384UL;
  if (ws_size < NEED) return;  // workspace too small: fail visibly (poison stays)

  _Float16* xgp = (_Float16*)(ws + OFF_XG);
  _Float16* xfp = (_Float16*)(ws + OFF_XB);
  _Float16* wxt = (_Float16*)(ws + OFF_WXT);
  _Float16* wht = (_Float16*)(ws + OFF_WHT);
  float*    bp  = (float*)(ws + OFF_BP);
  _Float16* hsl = (_Float16*)(ws + OFF_H);
  unsigned int* flg = (unsigned int*)(ws + OFF_FL);
  float* outp = (float*)d_out;

  hipMemsetAsync(ws + OFF_H, 0, 262144, stream);     // h_0 = 0 (parity-0 buffer)
  hipMemsetAsync(ws + OFF_FL, 0, 16384, stream);     // arrival counters = 0
  hipMemsetAsync(d_out, 0, sizeof(float) * 256, stream);

  k_prep<<<4096, 256, 0, stream>>>(x, Wx, Wh, b, xfp, wxt, wht, bp);
  k_gemm_xg<<<16384, 256, 0, stream>>>(xfp, wxt, bp, xgp);

  const _Float16* xgc = xgp;
  const _Float16* whtc = wht;
  void* args[] = { (void*)&xgc, (void*)&whtc, (void*)&Wfc, (void*)&bfc,
                   (void*)&hsl, (void*)&flg, (void*)&outp };
  hipLaunchCooperativeKernel((void*)k_scan, dim3(256), dim3(256), args, 0, stream);
}

// Round 5
// 1853.914 us; speedup vs baseline: 1.7049x; 1.0074x over previous
//
#include <hip/hip_runtime.h>
#include <hip/hip_bf16.h>

// LSTM: B=256, T=512, D=512, H=512, fp32 in/out, fp16 compute (fp32 accum).
//   k_prep    : cast x -> f16; transpose+permute Wx,Wh -> [n'][k] f16 (n' = j*4+gate); permute b.
//   k_gemm_xg : xg[b*T+t][n'] = x @ Wx + b   (m97-style 128x128 MFMA tile, f16 out)
//   k_scan    : cooperative, 16 groups x 16 blocks (XCD-local groups). Block s owns 32 hidden
//               units (128 gate cols) for its group's 16 batch rows. Wh slice pinned in VGPRs.
//               Swapped MFMA (A=Wh, B=h): lane gets full i,f,g,o quad per (m,j) -> no LDS tiles.
//               r10 = r9 flag protocol (proven: 1868us) + three serial-latency cuts:
//                 (1) own-flag skip: poll only the 15 REMOTE flags. Own block's
//                     completion is proven by the intra-block barrier (every wave
//                     acks its h store via vmcnt(0) BEFORE its LDS arrival-add,
//                     before the barrier). Removes ~1 MALL RT of self-gating/step.
//                 (2) LDS-aggregated publish: waves count arrivals in an LDS
//                     monotonic counter; the 4th finisher does ONE plain sc0 sc1
//                     flag store of (t+1) (was 4x global atomicAdd to one line ->
//                     RMW serialization at the MALL). Happens-before preserved:
//                     each wave's ack precedes its LDS add; publisher's store
//                     issues after observing all 4 adds.
//                 (3) xg prefetch 1 step ahead, issued BEFORE the poll: stragglers
//                     (whose poll passes instantly) never expose xg HBM latency
//                     on the serial chain.
//               Producer side otherwise unchanged: contiguous 16B/lane sc0 sc1 store
//               per wave -> s_waitcnt vmcnt(0) (ack at coherence point) -> publish.

typedef _Float16 half8 __attribute__((ext_vector_type(8)));
typedef _Float16 half4 __attribute__((ext_vector_type(4)));
typedef int int4v __attribute__((ext_vector_type(4)));
typedef float float4v __attribute__((ext_vector_type(4)));

__device__ __forceinline__ void gl_lds16(const void* g, void* l) {
  __builtin_amdgcn_global_load_lds(
      (const __attribute__((address_space(1))) unsigned int*)g,
      (__attribute__((address_space(3))) unsigned int*)l, 16, 0, 0);
}

__device__ __forceinline__ float sigm(float v) { return 1.f / (1.f + __expf(-v)); }
__device__ __forceinline__ float tanh_(float v) { return 1.f - 2.f / (__expf(2.f * v) + 1.f); }

// ---------------------------------------------------------------- k_prep
__global__ __launch_bounds__(256) void k_prep(
    const float* __restrict__ x, const float* __restrict__ Wx,
    const float* __restrict__ Wh, const float* __restrict__ b,
    _Float16* __restrict__ xf, _Float16* __restrict__ wxt,
    _Float16* __restrict__ wht, float* __restrict__ bp)
{
  const long NX8 = 67108864L / 8;   // x elems / 8
  const long NW  = 2048L * 512;     // one transposed weight matrix
  const long TOT = NX8 + 2 * NW + 2048;
  long stride = (long)gridDim.x * blockDim.x;
  for (long id = (long)blockIdx.x * blockDim.x + threadIdx.x; id < TOT; id += stride) {
    if (id < NX8) {
      const float4v* p = (const float4v*)x + id * 2;
      float4v a = p[0], c = p[1];
      half8 o;
      o[0]=(_Float16)a[0]; o[1]=(_Float16)a[1]; o[2]=(_Float16)a[2]; o[3]=(_Float16)a[3];
      o[4]=(_Float16)c[0]; o[5]=(_Float16)c[1]; o[6]=(_Float16)c[2]; o[7]=(_Float16)c[3];
      ((half8*)xf)[id] = o;
    } else if (id < NX8 + NW) {
      long e = id - NX8;
      int np = (int)(e >> 9), k = (int)(e & 511);
      int j = np >> 2, gt = np & 3;               // n' = j*4 + gate
      wxt[e] = (_Float16)Wx[(long)k * 2048 + gt * 512 + j];
    } else if (id < NX8 + 2 * NW) {
      long e = id - NX8 - NW;
      int np = (int)(e >> 9), k = (int)(e & 511);
      int j = np >> 2, gt = np & 3;
      wht[e] = (_Float16)Wh[(long)k * 2048 + gt * 512 + j];
    } else {
      int np = (int)(id - NX8 - 2 * NW);
      int j = np >> 2, gt = np & 3;
      bp[np] = b[gt * 512 + j];
    }
  }
}

// ---------------------------------------------------------------- k_gemm_xg
// C[M=131072][N=2048] = xf[M][512] @ wxt[N][512]^T + bp, f16 out.
__global__ __launch_bounds__(256, 2) void k_gemm_xg(
    const _Float16* __restrict__ xf, const _Float16* __restrict__ wxt,
    const float* __restrict__ bp, _Float16* __restrict__ xg)
{
  __shared__ _Float16 As[128 * 32];
  __shared__ _Float16 Bs[128 * 32];
  const int tid = threadIdx.x;
  const int w = tid >> 6, l = tid & 63;
  const int mt = blockIdx.x >> 4, nt = blockIdx.x & 15;
  const int qr = (w >> 1) * 64, qc = (w & 1) * 64;
  float4v acc[4][4];
  #pragma unroll
  for (int i = 0; i < 4; ++i)
    #pragma unroll
    for (int j = 0; j < 4; ++j) acc[i][j] = (float4v){0.f, 0.f, 0.f, 0.f};
  const int lr = l >> 2, lc = (l & 3) * 8;
  for (int kt = 0; kt < 16; ++kt) {
    __syncthreads();
    #pragma unroll
    for (int i = 0; i < 2; ++i) {
      int chunk = i * 4 + w;  // 16 rows x 64B per chunk; lane writes base + lane*16B
      gl_lds16(xf + ((long)(mt * 128 + chunk * 16 + lr)) * 512 + kt * 32 + lc, As + chunk * 512);
      gl_lds16(wxt + ((long)(nt * 128 + chunk * 16 + lr)) * 512 + kt * 32 + lc, Bs + chunk * 512);
    }
    __syncthreads();
    half8 af[4], bf[4];
    #pragma unroll
    for (int mi = 0; mi < 4; ++mi)
      af[mi] = *(const half8*)(As + (qr + mi * 16 + (l & 15)) * 32 + (l >> 4) * 8);
    #pragma unroll
    for (int ni = 0; ni < 4; ++ni)
      bf[ni] = *(const half8*)(Bs + (qc + ni * 16 + (l & 15)) * 32 + (l >> 4) * 8);
    #pragma unroll
    for (int mi = 0; mi < 4; ++mi)
      #pragma unroll
      for (int ni = 0; ni < 4; ++ni)
        acc[mi][ni] = __builtin_amdgcn_mfma_f32_16x16x32_f16(af[mi], bf[ni], acc[mi][ni], 0, 0, 0);
  }
  #pragma unroll
  for (int ni = 0; ni < 4; ++ni) {
    int col = nt * 128 + qc + ni * 16 + (l & 15);
    float bias = bp[col];
    #pragma unroll
    for (int mi = 0; mi < 4; ++mi) {
      long R0 = (long)mt * 128 + qr + mi * 16 + (l >> 4) * 4;
      #pragma unroll
      for (int r = 0; r < 4; ++r)
        xg[(R0 + r) * 2048 + col] = (_Float16)(acc[mi][ni][r] + bias);
    }
  }
}

// ---------------------------------------------------------------- k_scan
// hsl: f16 [2 parity][256 slices][512], slice = 1KB, layout [w4][m16][8j'].
// flags: u32 publish counters, 64B apart, flags[g*256 + s*16] = t+1 when block s
//        has published h_{t+1} (all 4 waves' stores acked at the coherence point).
__global__ __launch_bounds__(256, 1) void k_scan(
    const _Float16* __restrict__ xg, const _Float16* __restrict__ wht,
    const float* __restrict__ wfc, const float* __restrict__ bfc,
    _Float16* __restrict__ hsl, unsigned int* __restrict__ flags,
    float* __restrict__ out)
{
  __shared__ unsigned int wctr;   // monotonic wave-arrival counter (LDS publish agg)
  const int tid = threadIdx.x;
  if (tid == 0) wctr = 0;
  __syncthreads();

  const int w = tid >> 6, l = tid & 63;
  const int q = l >> 4;            // k-subslice selector / j-quad
  const int m = l & 15;            // batch row within group
  const int bb = blockIdx.x;
  const int slot = bb >> 3;
  const int g = (bb & 7) * 2 + (slot >> 4);   // XCD-local group placement (perf only)
  const int s = slot & 15;

  // Wh A-fragments, pinned in VGPRs. Tile nt=2w+e rows n' = s*128 + nt*16 + m, k = kk*32 + q*8..
  int4v bw0[16], bw1[16];
  {
    const _Float16* b0 = wht + ((long)(s * 128 + (2 * w + 0) * 16 + m)) * 512 + q * 8;
    const _Float16* b1 = wht + ((long)(s * 128 + (2 * w + 1) * 16 + m)) * 512 + q * 8;
    #pragma unroll
    for (int kk = 0; kk < 16; ++kk) {
      bw0[kk] = *(const int4v*)(b0 + kk * 32);
      bw1[kk] = *(const int4v*)(b1 + kk * 32);
    }
    #pragma unroll
    for (int kk = 0; kk < 16; ++kk)
      asm volatile("" : "+v"(bw0[kk]), "+v"(bw1[kk]));  // force residency; no remat
  }

  float c0 = 0.f, c1 = 0.f;
  const int j0 = s * 32 + 8 * w + q;              // this lane's two hidden units
  const int j1 = s * 32 + 8 * w + 4 + q;
  const float wf0 = wfc[j0], wf1 = wfc[j1];
  unsigned int* fl = flags + g * 256;             // 16 counters * 16 u32 stride (64B lines)
  const _Float16* xgr = xg + ((long)(g * 16 + m)) * 512 * 2048 + s * 128 + q * 4;
  const _Float16* hrg = hsl + (long)g * 8192 + q * 128 + m * 8;
  _Float16* hw = hsl + (long)(g * 16 + s) * 512 + w * 128 + m * 8;

  // xg for t=0 (prologue)
  half4 xc0 = *(const half4*)(xgr + (2 * w + 0) * 16);
  half4 xc1 = *(const half4*)(xgr + (2 * w + 1) * 16);

  for (int t = 0; t < 512; ++t) {
    const int pr = t & 1;
    // (3) prefetch NEXT step's xg, issued BEFORE the poll -> consumed next step
    // with a full step of latency cover; stragglers never expose xg latency.
    const long tn = (t < 511) ? (long)(t + 1) : 511L;
    const half4 xn0 = *(const half4*)(xgr + tn * 2048 + (2 * w + 0) * 16);
    const half4 xn1 = *(const half4*)(xgr + tn * 2048 + (2 * w + 1) * 16);
    if (t) {
      // (1) single-wave poll of the 15 REMOTE flags; own block's completion is
      // proven by the barrier (every wave acked its store before its LDS add).
      if (w == 0 && l < 16 && l != s) {
        unsigned int* p = fl + l * 16;
        while (__hip_atomic_load(p, __ATOMIC_RELAXED, __HIP_MEMORY_SCOPE_AGENT)
               < (unsigned)t) {}
      }
      asm volatile("" ::: "memory");   // compile-time order only; no cache ops
      __syncthreads();
    }
    // load group's h_t as 16x16B sc0 sc1 loads (coherence-point reads, issued
    // strictly after flag observation -> producers' acked data is visible).
    const _Float16* hr = hrg + pr * 131072;
    int4v av[16];
    #pragma unroll
    for (int kk = 0; kk < 16; ++kk)
      asm volatile("global_load_dwordx4 %0, %1, off sc0 sc1"
                   : "=&v"(av[kk]) : "v"(hr + kk * 512) : "memory");
    asm volatile("s_waitcnt vmcnt(0)" ::: "memory");
    __builtin_amdgcn_sched_barrier(0);   // rule #18: no MFMA hoist past the waitcnt

    float4v a0 = (float4v){0.f,0.f,0.f,0.f}, a1 = a0, b0v = a0, b1v = a0;
    #pragma unroll
    for (int kk = 0; kk < 8; ++kk) {
      a0 = __builtin_amdgcn_mfma_f32_16x16x32_f16(__builtin_bit_cast(half8, bw0[kk]),
                                                  __builtin_bit_cast(half8, av[kk]), a0, 0, 0, 0);
      a1 = __builtin_amdgcn_mfma_f32_16x16x32_f16(__builtin_bit_cast(half8, bw1[kk]),
                                                  __builtin_bit_cast(half8, av[kk]), a1, 0, 0, 0);
    }
    #pragma unroll
    for (int kk = 8; kk < 16; ++kk) {
      b0v = __builtin_amdgcn_mfma_f32_16x16x32_f16(__builtin_bit_cast(half8, bw0[kk]),
                                                   __builtin_bit_cast(half8, av[kk]), b0v, 0, 0, 0);
      b1v = __builtin_amdgcn_mfma_f32_16x16x32_f16(__builtin_bit_cast(half8, bw1[kk]),
                                                   __builtin_bit_cast(half8, av[kk]), b1v, 0, 0, 0);
    }
    a0 += b0v; a1 += b1v;
    // lane holds full gate quad (i,f,g,o) for (m, j0) in a0 and (m, j1) in a1
    float i0 = sigm(a0[0] + (float)xc0[0]);
    float f0 = sigm(a0[1] + (float)xc0[1]);
    float g0 = tanh_(a0[2] + (float)xc0[2]);
    float o0 = sigm(a0[3] + (float)xc0[3]);
    c0 = f0 * c0 + i0 * g0;
    float h0v = o0 * tanh_(c0);
    float i1 = sigm(a1[0] + (float)xc1[0]);
    float f1 = sigm(a1[1] + (float)xc1[1]);
    float g1 = tanh_(a1[2] + (float)xc1[2]);
    float o1 = sigm(a1[3] + (float)xc1[3]);
    c1 = f1 * c1 + i1 * g1;
    float h1v = o1 * tanh_(c1);
    // gather 8 f16 (j' = 8w..8w+7 for row m) into lane q==0, publish one 16B coherent store
    unsigned int hb0 = (unsigned int)__builtin_bit_cast(unsigned short, (_Float16)h0v);
    unsigned int hb1 = (unsigned int)__builtin_bit_cast(unsigned short, (_Float16)h1v);
    unsigned int pb0 = __shfl_xor(hb0, 16);
    unsigned int pb1 = __shfl_xor(hb1, 16);
    unsigned int pair0 = hb0 | (pb0 << 16);   // (8w+q, 8w+q+1) at even q
    unsigned int pair1 = hb1 | (pb1 << 16);   // (8w+4+q, 8w+5+q) at even q
    unsigned int x0 = __shfl_xor(pair0, 32);  // q=0 <-> q=2
    unsigned int x1 = __shfl_xor(pair1, 32);
    if (q == 0) {
      int4v pk = {(int)pair0, (int)x0, (int)pair1, (int)x1};  // j' 0..7 of this wave's block
      _Float16* dst = hw + (pr ^ 1) * 131072;
      asm volatile("global_store_dwordx4 %0, %1, off sc0 sc1"
                   :: "v"(dst), "v"(pk) : "memory");
    }
    if (t == 511) {
      float part = h0v * wf0 + h1v * wf1;
      part += __shfl_xor(part, 16);
      part += __shfl_xor(part, 32);
      if (l < 16) {
        float v = part;
        if (s == 0 && w == 0) v += bfc[0];
        atomicAdd(out + g * 16 + l, v);
      }
    } else {
      // release: coherent stores ACK at coherence point; (2) LDS-aggregated
      // publish: 4th-arriving wave does ONE plain flag store of t+1.
      asm volatile("s_waitcnt vmcnt(0)" ::: "memory");
      if (l == 0) {
        unsigned int old = atomicAdd(&wctr, 1u);
        if (old == 4u * (unsigned)t + 3u)
          __hip_atomic_store(fl + s * 16, (unsigned)(t + 1),
                             __ATOMIC_RELAXED, __HIP_MEMORY_SCOPE_AGENT);
      }
    }
    xc0 = xn0; xc1 = xn1;
  }
}

// ---------------------------------------------------------------- launch
extern "C" void kernel_launch(void* const* d_in, const int* in_sizes, int n_in,
                              void* d_out, int out_size, void* d_ws, size_t ws_size,
                              hipStream_t stream)
{
  const float* x   = (const float*)d_in[0];
  const float* Wx  = (const float*)d_in[1];
  const float* Wh  = (const float*)d_in[2];
  const float* b   = (const float*)d_in[3];
  const float* Wfc = (const float*)d_in[4];
  const float* bfc = (const float*)d_in[5];
  char* ws = (char*)d_ws;

  const size_t OFF_XG  = 0;                          // f16 [131072][2048] = 512MB
  const size_t OFF_XB  = 536870912UL;                // f16 x          = 128MB
  const size_t OFF_WXT = OFF_XB + 134217728UL;       // f16 [2048][512] = 2MB
  const size_t OFF_WHT = OFF_WXT + 2097152UL;        // f16 [2048][512] = 2MB
  const size_t OFF_BP  = OFF_WHT + 2097152UL;        // f32 [2048]
  const size_t OFF_H   = OFF_BP + 8192UL;            // f16 [2][256][512] = 512KB
  const size_t OFF_FL  = OFF_H + 524288UL;           // u32 flags, 64B apart = 16KB
  const size_t NEED    = OFF_FL + 16384UL;
  if (ws_size < NEED) return;  // workspace too small: fail visibly (poison stays)

  _Float16* xgp = (_Float16*)(ws + OFF_XG);
  _Float16* xfp = (_Float16*)(ws + OFF_XB);
  _Float16* wxt = (_Float16*)(ws + OFF_WXT);
  _Float16* wht = (_Float16*)(ws + OFF_WHT);
  float*    bp  = (float*)(ws + OFF_BP);
  _Float16* hsl = (_Float16*)(ws + OFF_H);
  unsigned int* flg = (unsigned int*)(ws + OFF_FL);
  float* outp = (float*)d_out;

  hipMemsetAsync(ws + OFF_H, 0, 262144, stream);     // h_0 = 0 (parity-0 buffer)
  hipMemsetAsync(ws + OFF_FL, 0, 16384, stream);     // publish counters = 0
  hipMemsetAsync(d_out, 0, sizeof(float) * 256, stream);

  k_prep<<<4096, 256, 0, stream>>>(x, Wx, Wh, b, xfp, wxt, wht, bp);
  k_gemm_xg<<<16384, 256, 0, stream>>>(xfp, wxt, bp, xgp);

  const _Float16* xgc = xgp;
  const _Float16* whtc = wht;
  void* args[] = { (void*)&xgc, (void*)&whtc, (void*)&Wfc, (void*)&bfc,
                   (void*)&hsl, (void*)&flg, (void*)&outp };
  hipLaunchCooperativeKernel((void*)k_scan, dim3(256), dim3(256), args, 0, stream);
}